// Round 1
// baseline (159.681 us; speedup 1.0000x reference)
//
#include <hip/hip_runtime.h>
#include <math.h>

#define D 256
#define Q 256
#define I 2048
#define QT 4
#define IT 1024

__device__ __forceinline__ float block_reduce_sum(float v) {
    // 256 threads = 4 waves of 64
    for (int off = 32; off > 0; off >>= 1)
        v += __shfl_down(v, off, 64);
    __shared__ float tmp[4];
    int lane = threadIdx.x & 63;
    int wid  = threadIdx.x >> 6;
    __syncthreads();               // protect tmp from previous use
    if (lane == 0) tmp[wid] = v;
    __syncthreads();
    return tmp[0] + tmp[1] + tmp[2] + tmp[3];
}

__device__ __forceinline__ float sigmoidf_(float x) {
    return 1.0f / (1.0f + expf(-x));
}

// One block per query q; threadIdx.x = d in [0,256)
__global__ void prep_query(const float* __restrict__ qf,
                           const float* __restrict__ qif,
                           const float* __restrict__ gamma,
                           const float* __restrict__ beta,
                           const float* __restrict__ mean,
                           const float* __restrict__ var,
                           float* __restrict__ p,
                           float* __restrict__ w,
                           float* __restrict__ v2,
                           float* __restrict__ sq,
                           float* __restrict__ ccp) {
    int q = blockIdx.x;
    int d = threadIdx.x;

    // xq = l2n(query_feats[q])
    float x = qf[q * D + d];
    float nx = block_reduce_sum(x * x);
    float xn = x / fmaxf(sqrtf(nx), 1e-12f);
    float gate = sigmoidf_(xn * 5.0f);   // sigmoid(xq / 0.2)

    // yq = l2n(query_img_feats[q])
    float y = qif[q * D + d];
    float ny = block_reduce_sum(y * y);
    float yn = y / fmaxf(sqrtf(ny), 1e-12f);

    float is = gamma[d] * rsqrtf(var[d] + 1e-5f);
    float c  = beta[d] - mean[d] * is;
    float a  = gate * is;

    // fused_query = bn(yq*gate) = yn*a + c ; u = l2n(fused_query)
    float f = yn * a + c;
    float nf = block_reduce_sum(f * f);
    float u = f / fmaxf(sqrtf(nf), 1e-12f);

    p[q * D + d]  = u * a;
    w[q * D + d]  = a * a;
    v2[q * D + d] = 2.0f * a * c;

    float s = block_reduce_sum(u * c);
    if (d == 0) sq[q] = s;

    if (q == 0) {
        float ccs = block_reduce_sum(c * c);
        if (d == 0) *ccp = ccs;
    }
}

// One block per gallery item i; threadIdx.x = d. Writes normalized row transposed.
__global__ void prep_gallery(const float* __restrict__ g,
                             float* __restrict__ ygT) {
    int i = blockIdx.x;
    int d = threadIdx.x;
    float x = g[i * D + d];
    float n = block_reduce_sum(x * x);
    float xn = x / fmaxf(sqrtf(n), 1e-12f);
    ygT[d * I + i] = xn;
}

// Main: block = 256 threads; tile = QT queries x IT items.
// grid = (Q/QT, I/IT)
__global__ void __launch_bounds__(256)
main_scores(const float* __restrict__ ygT,
            const float* __restrict__ p,
            const float* __restrict__ w,
            const float* __restrict__ v2,
            const float* __restrict__ sq,
            const float* __restrict__ ccp,
            float* __restrict__ out) {
    __shared__ float sp[QT][D];
    __shared__ float sw[QT][D];
    __shared__ float sv[QT][D];
    __shared__ float ssq[QT];

    int q0 = blockIdx.x * QT;
    int i0 = blockIdx.y * IT;
    int t = threadIdx.x;

    for (int qq = 0; qq < QT; qq++) {
        sp[qq][t] = p [(q0 + qq) * D + t];
        sw[qq][t] = w [(q0 + qq) * D + t];
        sv[qq][t] = v2[(q0 + qq) * D + t];
    }
    if (t < QT) ssq[t] = sq[q0 + t];
    float cc = *ccp;
    __syncthreads();

    float acc1[QT][4];
    float acc2[QT][4];
#pragma unroll
    for (int qq = 0; qq < QT; qq++)
#pragma unroll
        for (int j = 0; j < 4; j++) { acc1[qq][j] = 0.f; acc2[qq][j] = 0.f; }

    int ib = i0 + 4 * t;

    for (int d = 0; d < D; d++) {
        float4 yv = *(const float4*)&ygT[d * I + ib];
        float y2x = yv.x * yv.x, y2y = yv.y * yv.y,
              y2z = yv.z * yv.z, y2w = yv.w * yv.w;
#pragma unroll
        for (int qq = 0; qq < QT; qq++) {
            float pp = sp[qq][d];
            float ww = sw[qq][d];
            float vv = sv[qq][d];
            acc1[qq][0] += pp * yv.x;
            acc1[qq][1] += pp * yv.y;
            acc1[qq][2] += pp * yv.z;
            acc1[qq][3] += pp * yv.w;
            acc2[qq][0] += ww * y2x + vv * yv.x;
            acc2[qq][1] += ww * y2y + vv * yv.y;
            acc2[qq][2] += ww * y2z + vv * yv.z;
            acc2[qq][3] += ww * y2w + vv * yv.w;
        }
    }

#pragma unroll
    for (int qq = 0; qq < QT; qq++) {
        float s = ssq[qq];
        float4 o;
        float n0 = fmaxf(sqrtf(fmaxf(acc2[qq][0] + cc, 0.f)), 1e-12f);
        float n1 = fmaxf(sqrtf(fmaxf(acc2[qq][1] + cc, 0.f)), 1e-12f);
        float n2 = fmaxf(sqrtf(fmaxf(acc2[qq][2] + cc, 0.f)), 1e-12f);
        float n3 = fmaxf(sqrtf(fmaxf(acc2[qq][3] + cc, 0.f)), 1e-12f);
        o.x = sigmoidf_((acc1[qq][0] + s) / n0);
        o.y = sigmoidf_((acc1[qq][1] + s) / n1);
        o.z = sigmoidf_((acc1[qq][2] + s) / n2);
        o.w = sigmoidf_((acc1[qq][3] + s) / n3);
        *(float4*)&out[(q0 + qq) * I + ib] = o;
    }
}

extern "C" void kernel_launch(void* const* d_in, const int* in_sizes, int n_in,
                              void* d_out, int out_size, void* d_ws, size_t ws_size,
                              hipStream_t stream) {
    const float* qf    = (const float*)d_in[0]; // [Q,D]
    const float* qif   = (const float*)d_in[1]; // [Q,D]
    const float* gal   = (const float*)d_in[2]; // [I,D]
    const float* gamma = (const float*)d_in[3];
    const float* beta  = (const float*)d_in[4];
    const float* mean  = (const float*)d_in[5];
    const float* var   = (const float*)d_in[6];
    float* out = (float*)d_out;                 // [Q,I]

    float* ws = (float*)d_ws;
    float* p   = ws;                       // Q*D
    float* w   = p  + Q * D;               // Q*D
    float* v2  = w  + Q * D;               // Q*D
    float* ygT = v2 + Q * D;               // D*I
    float* sq  = ygT + D * I;              // Q
    float* cc  = sq + Q;                   // 1

    prep_query<<<Q, D, 0, stream>>>(qf, qif, gamma, beta, mean, var, p, w, v2, sq, cc);
    prep_gallery<<<I, D, 0, stream>>>(gal, ygT);
    main_scores<<<dim3(Q / QT, I / IT), 256, 0, stream>>>(ygT, p, w, v2, sq, cc, out);
}

// Round 2
// 90.210 us; speedup vs baseline: 1.7701x; 1.7701x over previous
//
#include <hip/hip_runtime.h>
#include <math.h>

#define D 256
#define Q 256
#define I 2048

__device__ __forceinline__ float wave_sum(float v) {
#pragma unroll
    for (int off = 1; off < 64; off <<= 1)
        v += __shfl_xor(v, off, 64);
    return v;
}

__device__ __forceinline__ float sigmoidf_(float x) {
    return 1.0f / (1.0f + expf(-x));
}

// grid.x in [0,64): gallery transpose+normalize blocks (32 rows each)
// grid.x in [64,128): query prep blocks (4 queries each, one per wave)
__global__ void __launch_bounds__(256)
prep_all(const float* __restrict__ qf,
         const float* __restrict__ qif,
         const float* __restrict__ gal,
         const float* __restrict__ gamma,
         const float* __restrict__ beta,
         const float* __restrict__ mean,
         const float* __restrict__ var,
         float* __restrict__ p,
         float* __restrict__ w,
         float* __restrict__ v2,
         float* __restrict__ ygT,
         float* __restrict__ sq,
         float* __restrict__ ccp) {
    const int t = threadIdx.x;
    const int wv = t >> 6;      // wave id 0..3
    const int l  = t & 63;      // lane

    if (blockIdx.x < 64) {
        // ---- gallery: normalize 32 rows and write transposed ----
        __shared__ float tile[32][257];   // +1 pad breaks bank conflicts
        __shared__ float sinv[32];
        const int i0 = blockIdx.x * 32;
        const float4* g4 = (const float4*)gal;   // row = 64 float4s

        // stage 32 rows, coalesced (wave stages one row per step)
#pragma unroll
        for (int c = 0; c < 8; c++) {
            int row = c * 4 + wv;
            float4 r = g4[(size_t)(i0 + row) * 64 + l];
            *(float4*)&tile[row][4 * l] = r;
        }
        __syncthreads();

        // per-row inverse norm (wave handles 8 rows)
#pragma unroll
        for (int k = 0; k < 8; k++) {
            int row = k * 4 + wv;
            float4 v = *(const float4*)&tile[row][4 * l];
            float s = wave_sum(v.x * v.x + v.y * v.y + v.z * v.z + v.w * v.w);
            if (l == 0) sinv[row] = 1.0f / fmaxf(sqrtf(s), 1e-12f);
        }
        __syncthreads();

        // write transposed: ygT[d][i0+col], 2x128B contiguous per store instr
        const int half = l >> 5, col = l & 31;
        const float si = sinv[col];
#pragma unroll
        for (int c = 0; c < 32; c++) {
            int d = c * 8 + wv * 2 + half;
            ygT[(size_t)d * I + i0 + col] = tile[col][d] * si;
        }
    } else {
        // ---- query prep: one query per wave, lane holds d = 4l..4l+3 ----
        const int q = (blockIdx.x - 64) * 4 + wv;
        const float4* qf4  = (const float4*)qf;
        const float4* qif4 = (const float4*)qif;
        const float4* ga4  = (const float4*)gamma;
        const float4* be4  = (const float4*)beta;
        const float4* me4  = (const float4*)mean;
        const float4* va4  = (const float4*)var;

        float4 x = qf4[(size_t)q * 64 + l];
        float nx = wave_sum(x.x * x.x + x.y * x.y + x.z * x.z + x.w * x.w);
        float inx = 1.0f / fmaxf(sqrtf(nx), 1e-12f);
        float g0 = sigmoidf_(x.x * inx * 5.0f);
        float g1 = sigmoidf_(x.y * inx * 5.0f);
        float g2 = sigmoidf_(x.z * inx * 5.0f);
        float g3 = sigmoidf_(x.w * inx * 5.0f);

        float4 y = qif4[(size_t)q * 64 + l];
        float ny = wave_sum(y.x * y.x + y.y * y.y + y.z * y.z + y.w * y.w);
        float iny = 1.0f / fmaxf(sqrtf(ny), 1e-12f);

        float4 gm = ga4[l], bt = be4[l], mn = me4[l], vr = va4[l];
        float is0 = gm.x * rsqrtf(vr.x + 1e-5f);
        float is1 = gm.y * rsqrtf(vr.y + 1e-5f);
        float is2 = gm.z * rsqrtf(vr.z + 1e-5f);
        float is3 = gm.w * rsqrtf(vr.w + 1e-5f);
        float c0 = bt.x - mn.x * is0;
        float c1 = bt.y - mn.y * is1;
        float c2 = bt.z - mn.z * is2;
        float c3 = bt.w - mn.w * is3;
        float a0 = g0 * is0, a1 = g1 * is1, a2 = g2 * is2, a3 = g3 * is3;

        float f0 = y.x * iny * a0 + c0;
        float f1 = y.y * iny * a1 + c1;
        float f2 = y.z * iny * a2 + c2;
        float f3 = y.w * iny * a3 + c3;
        float nf = wave_sum(f0 * f0 + f1 * f1 + f2 * f2 + f3 * f3);
        float inf_ = 1.0f / fmaxf(sqrtf(nf), 1e-12f);
        float u0 = f0 * inf_, u1 = f1 * inf_, u2 = f2 * inf_, u3 = f3 * inf_;

        float4 pw = make_float4(u0 * a0, u1 * a1, u2 * a2, u3 * a3);
        float4 ww = make_float4(a0 * a0, a1 * a1, a2 * a2, a3 * a3);
        float4 vv = make_float4(2.0f * a0 * c0, 2.0f * a1 * c1,
                                2.0f * a2 * c2, 2.0f * a3 * c3);
        ((float4*)p)[(size_t)q * 64 + l]  = pw;
        ((float4*)w)[(size_t)q * 64 + l]  = ww;
        ((float4*)v2)[(size_t)q * 64 + l] = vv;

        float s = wave_sum(u0 * c0 + u1 * c1 + u2 * c2 + u3 * c3);
        if (l == 0) sq[q] = s;

        if (q == 0) {
            float ccs = wave_sum(c0 * c0 + c1 * c1 + c2 * c2 + c3 * c3);
            if (l == 0) *ccp = ccs;
        }
    }
}

// acc1 += P*y ; t = W*y + V ; acc2 += y*t   (3 FMA per element, no y^2 mul)
#define ACC_STEP(yv, P_, W_, V_)                 \
    {                                            \
        a1.x += (P_) * yv.x;                     \
        a1.y += (P_) * yv.y;                     \
        a1.z += (P_) * yv.z;                     \
        a1.w += (P_) * yv.w;                     \
        float t0 = (W_) * yv.x + (V_);           \
        float t1 = (W_) * yv.y + (V_);           \
        float t2 = (W_) * yv.z + (V_);           \
        float t3 = (W_) * yv.w + (V_);           \
        a2.x += yv.x * t0;                       \
        a2.y += yv.y * t1;                       \
        a2.z += yv.z * t2;                       \
        a2.w += yv.w * t3;                       \
    }

// grid = (Q/4, I/256); block = 256. Wave = 1 query x 256 items (4/thread).
// p/w/v2 reads are wave-uniform -> scalar loads; no LDS at all.
__global__ void __launch_bounds__(256)
main_scores(const float* __restrict__ ygT,
            const float* __restrict__ p,
            const float* __restrict__ w,
            const float* __restrict__ v2,
            const float* __restrict__ sq,
            const float* __restrict__ ccp,
            float* __restrict__ out) {
    const int t = threadIdx.x, wv = t >> 6, lane = t & 63;
    const int q = __builtin_amdgcn_readfirstlane(blockIdx.x * 4 + wv);
    const float4* __restrict__ P = (const float4*)(p + (size_t)q * D);
    const float4* __restrict__ W = (const float4*)(w + (size_t)q * D);
    const float4* __restrict__ V = (const float4*)(v2 + (size_t)q * D);
    const float4* __restrict__ Yg = (const float4*)ygT;   // [D][I/4]
    const int icol = blockIdx.y * 64 + lane;              // float4 col in [0,512)

    float4 a1 = make_float4(0.f, 0.f, 0.f, 0.f);
    float4 a2 = make_float4(0.f, 0.f, 0.f, 0.f);

#pragma unroll 2
    for (int dc = 0; dc < 64; ++dc) {
        float4 pp = P[dc], ww = W[dc], vv = V[dc];
        const float4* yb = Yg + (size_t)(dc * 4) * (I / 4) + icol;
        float4 y0 = yb[0 * (I / 4)];
        float4 y1 = yb[1 * (I / 4)];
        float4 y2 = yb[2 * (I / 4)];
        float4 y3 = yb[3 * (I / 4)];
        ACC_STEP(y0, pp.x, ww.x, vv.x);
        ACC_STEP(y1, pp.y, ww.y, vv.y);
        ACC_STEP(y2, pp.z, ww.z, vv.z);
        ACC_STEP(y3, pp.w, ww.w, vv.w);
    }

    const float s = sq[q];
    const float cc = *ccp;
    float4 o;
    o.x = sigmoidf_((a1.x + s) / fmaxf(sqrtf(fmaxf(a2.x + cc, 0.f)), 1e-12f));
    o.y = sigmoidf_((a1.y + s) / fmaxf(sqrtf(fmaxf(a2.y + cc, 0.f)), 1e-12f));
    o.z = sigmoidf_((a1.z + s) / fmaxf(sqrtf(fmaxf(a2.z + cc, 0.f)), 1e-12f));
    o.w = sigmoidf_((a1.w + s) / fmaxf(sqrtf(fmaxf(a2.w + cc, 0.f)), 1e-12f));
    ((float4*)out)[(size_t)q * (I / 4) + icol] = o;
}

extern "C" void kernel_launch(void* const* d_in, const int* in_sizes, int n_in,
                              void* d_out, int out_size, void* d_ws, size_t ws_size,
                              hipStream_t stream) {
    const float* qf    = (const float*)d_in[0]; // [Q,D]
    const float* qif   = (const float*)d_in[1]; // [Q,D]
    const float* gal   = (const float*)d_in[2]; // [I,D]
    const float* gamma = (const float*)d_in[3];
    const float* beta  = (const float*)d_in[4];
    const float* mean  = (const float*)d_in[5];
    const float* var   = (const float*)d_in[6];
    float* out = (float*)d_out;                 // [Q,I]

    float* ws  = (float*)d_ws;
    float* p   = ws;                        // Q*D
    float* w   = p  + Q * D;                // Q*D
    float* v2  = w  + Q * D;                // Q*D
    float* ygT = v2 + Q * D;                // D*I
    float* sq  = ygT + (size_t)D * I;       // Q
    float* cc  = sq + Q;                    // 1

    prep_all<<<128, 256, 0, stream>>>(qf, qif, gal, gamma, beta, mean, var,
                                      p, w, v2, ygT, sq, cc);
    main_scores<<<dim3(Q / 4, I / 256), 256, 0, stream>>>(ygT, p, w, v2, sq, cc, out);
}